// Round 2
// baseline (41.641 us; speedup 1.0000x reference)
//
#include <hip/hip_runtime.h>

#define BATCH   1024
#define IN_DIM  512
#define OUT_DIM 256
#define RB      4    // batch rows per block
#define U       8    // k-unroll per half-body (two half-bodies in flight)

// Fused tropical block, register-pipelined.
//   h1 = min_plus(x, W1); out = max_i(h1+W2) + b2
//   hm = min_plus(x, Wm); sc  = max_i(hm+Ws) + bs
//   result = min(out, sc)
// Thread = output column j; block = 256 threads covering RB=4 batch rows.
// Grid = 256 blocks (1/CU). Latency hidden via explicit A/B register
// double-buffering of weight loads (prefetch distance = one 8-k half-body,
// ~128 VALU instrs ≈ 256 cy). x rows staged once in LDS (uniform broadcast
// reads in the hot loop). L2 weight traffic = 256 blocks x 1.5 MB = 393 MB.
__global__ __launch_bounds__(256, 2) void tropical_fused(
    const float* __restrict__ x,
    const float* __restrict__ W1,
    const float* __restrict__ W2,
    const float* __restrict__ b2,
    const float* __restrict__ Wm,
    const float* __restrict__ Ws,
    const float* __restrict__ bs,
    float* __restrict__ out)
{
    const int j    = threadIdx.x;
    const int row0 = blockIdx.x * RB;

    __shared__ float xs[RB * IN_DIM];      // 8 KB: the block's 4 x rows
    __shared__ float hs1[RB][OUT_DIM];     // 4 KB: min_plus(x,W1)
    __shared__ float hsm[RB][OUT_DIM];     // 4 KB: min_plus(x,Wm)

    // ---- stage x rows into LDS (coalesced float4, 2 per thread) ----
    {
        const float4* src = (const float4*)(x + (size_t)row0 * IN_DIM);
        float4*       dst = (float4*)xs;
        dst[j]       = src[j];
        dst[j + 256] = src[j + 256];
    }
    __syncthreads();

    const float INF = __builtin_huge_valf();

    // ================= stage 1: min-plus, K = IN_DIM =================
    float a1[RB], am[RB];
    #pragma unroll
    for (int r = 0; r < RB; ++r) { a1[r] = INF; am[r] = INF; }

    const float* W1j = W1 + j;
    const float* Wmj = Wm + j;

    float wA1[U], wAm[U], wB1[U], wBm[U];

    #pragma unroll
    for (int u = 0; u < U; ++u) {           // prologue: fill A with k=0..U-1
        wA1[u] = W1j[(size_t)u * OUT_DIM];
        wAm[u] = Wmj[(size_t)u * OUT_DIM];
    }

    for (int k = 0; k < IN_DIM; k += 2 * U) {
        // issue loads for half B (k+U)
        #pragma unroll
        for (int u = 0; u < U; ++u) {
            wB1[u] = W1j[(size_t)(k + U + u) * OUT_DIM];
            wBm[u] = Wmj[(size_t)(k + U + u) * OUT_DIM];
        }
        // compute half A (k .. k+U-1)
        #pragma unroll
        for (int u = 0; u < U; ++u) {
            #pragma unroll
            for (int r = 0; r < RB; ++r) {
                const float xv = xs[r * IN_DIM + k + u];
                a1[r] = fminf(a1[r], xv + wA1[u]);
                am[r] = fminf(am[r], xv + wAm[u]);
            }
        }
        // issue loads for next half A (k+2U); harmless wrap at the tail
        const int kn = (k + 2 * U < IN_DIM) ? (k + 2 * U) : 0;
        #pragma unroll
        for (int u = 0; u < U; ++u) {
            wA1[u] = W1j[(size_t)(kn + u) * OUT_DIM];
            wAm[u] = Wmj[(size_t)(kn + u) * OUT_DIM];
        }
        // compute half B (k+U .. k+2U-1)
        #pragma unroll
        for (int u = 0; u < U; ++u) {
            #pragma unroll
            for (int r = 0; r < RB; ++r) {
                const float xv = xs[r * IN_DIM + k + U + u];
                a1[r] = fminf(a1[r], xv + wB1[u]);
                am[r] = fminf(am[r], xv + wBm[u]);
            }
        }
    }

    #pragma unroll
    for (int r = 0; r < RB; ++r) { hs1[r][j] = a1[r]; hsm[r][j] = am[r]; }
    __syncthreads();

    // ================= stage 2: max-plus, K = OUT_DIM =================
    float c1[RB], cm[RB];
    #pragma unroll
    for (int r = 0; r < RB; ++r) { c1[r] = -INF; cm[r] = -INF; }

    const float* W2j = W2 + j;
    const float* Wsj = Ws + j;

    #pragma unroll
    for (int u = 0; u < U; ++u) {           // prologue
        wA1[u] = W2j[(size_t)u * OUT_DIM];
        wAm[u] = Wsj[(size_t)u * OUT_DIM];
    }

    for (int k = 0; k < OUT_DIM; k += 2 * U) {
        #pragma unroll
        for (int u = 0; u < U; ++u) {
            wB1[u] = W2j[(size_t)(k + U + u) * OUT_DIM];
            wBm[u] = Wsj[(size_t)(k + U + u) * OUT_DIM];
        }
        #pragma unroll
        for (int u = 0; u < U; ++u) {
            #pragma unroll
            for (int r = 0; r < RB; ++r) {
                c1[r] = fmaxf(c1[r], hs1[r][k + u] + wA1[u]);
                cm[r] = fmaxf(cm[r], hsm[r][k + u] + wAm[u]);
            }
        }
        const int kn = (k + 2 * U < OUT_DIM) ? (k + 2 * U) : 0;
        #pragma unroll
        for (int u = 0; u < U; ++u) {
            wA1[u] = W2j[(size_t)(kn + u) * OUT_DIM];
            wAm[u] = Wsj[(size_t)(kn + u) * OUT_DIM];
        }
        #pragma unroll
        for (int u = 0; u < U; ++u) {
            #pragma unroll
            for (int r = 0; r < RB; ++r) {
                c1[r] = fmaxf(c1[r], hs1[r][k + U + u] + wB1[u]);
                cm[r] = fmaxf(cm[r], hsm[r][k + U + u] + wBm[u]);
            }
        }
    }

    // ---- epilogue: bias + residual min, coalesced stores ----
    const float bb2 = b2[j];
    const float bbs = bs[j];
    #pragma unroll
    for (int r = 0; r < RB; ++r) {
        out[(size_t)(row0 + r) * OUT_DIM + j] = fminf(c1[r] + bb2, cm[r] + bbs);
    }
}

extern "C" void kernel_launch(void* const* d_in, const int* in_sizes, int n_in,
                              void* d_out, int out_size, void* d_ws, size_t ws_size,
                              hipStream_t stream) {
    const float* x  = (const float*)d_in[0];
    const float* W1 = (const float*)d_in[1];
    const float* W2 = (const float*)d_in[2];
    const float* b2 = (const float*)d_in[3];
    const float* Wm = (const float*)d_in[4];
    const float* Ws = (const float*)d_in[5];
    const float* bs = (const float*)d_in[6];
    float* out = (float*)d_out;

    dim3 grid(BATCH / RB);   // 256 blocks = 1 per CU
    dim3 block(OUT_DIM);     // thread per output column
    tropical_fused<<<grid, block, 0, stream>>>(x, W1, W2, b2, Wm, Ws, bs, out);
}

// Round 3
// 31.098 us; speedup vs baseline: 1.3390x; 1.3390x over previous
//
#include <hip/hip_runtime.h>

#define BATCH   1024
#define IN_DIM  512
#define OUT_DIM 256
#define RB      4      // batch rows per block
#define KC      8      // k-chunks (threadIdx.y)
#define JP      128    // column-pairs (threadIdx.x); each thread owns 2 cols

// Fused tropical block, split-K, 1024-thread blocks, 1 block/CU (grid=256).
//   h1 = min_plus(x, W1); out = max_i(h1+W2) + b2
//   hm = min_plus(x, Wm); sc  = max_i(hm+Ws) + bs
//   result = min(out, sc)
// Thread (jp, c): columns {2jp, 2jp+1}, k-chunk c.
//  - weights: float2 loads (halves VMEM instr count; coalesced 512B/wave)
//  - x: wave-uniform address -> scalar s_load, operands straight from SGPR
//  - min3/max3 idiom: fminf(acc, fminf(t0,t1)) -> v_min3_f32
//  - split-K partials reduced via one 64KB LDS buffer; stage-1 h kept
//    in-place in part[0] (each reduce thread rewrites only its own slot)
__global__ __launch_bounds__(1024, 4) void tropical_fused(
    const float* __restrict__ x,
    const float* __restrict__ W1,
    const float* __restrict__ W2,
    const float* __restrict__ b2,
    const float* __restrict__ Wm,
    const float* __restrict__ Ws,
    const float* __restrict__ bs,
    float* __restrict__ out)
{
    const int jp   = threadIdx.x;                                  // 0..127
    const int c    = __builtin_amdgcn_readfirstlane(threadIdx.y);  // 0..7, wave-uniform
    const int j0   = jp * 2;
    const int row0 = blockIdx.x * RB;

    // [chunk][path][row][colpair] = 8*2*4*128 float2 = 64 KB
    __shared__ float2 part[KC][2][RB][JP];

    const float INF = __builtin_huge_valf();

    // ================= stage 1: min-plus, K = 512, chunk = 64 k =================
    const float* W1p = W1 + j0;
    const float* Wmp = Wm + j0;

    float2 a1[RB], am[RB];
    #pragma unroll
    for (int r = 0; r < RB; ++r) {
        a1[r].x = INF; a1[r].y = INF;
        am[r].x = INF; am[r].y = INF;
    }

    const int kb = c * (IN_DIM / KC);   // 64-wide chunk

    #pragma unroll 4
    for (int kk = 0; kk < IN_DIM / KC; kk += 2) {
        const int k = kb + kk;
        const float2 w1a = *(const float2*)(W1p + (size_t)k       * OUT_DIM);
        const float2 w1b = *(const float2*)(W1p + (size_t)(k + 1) * OUT_DIM);
        const float2 wma = *(const float2*)(Wmp + (size_t)k       * OUT_DIM);
        const float2 wmb = *(const float2*)(Wmp + (size_t)(k + 1) * OUT_DIM);
        #pragma unroll
        for (int r = 0; r < RB; ++r) {
            const float x0 = x[(size_t)(row0 + r) * IN_DIM + k];     // s_load (uniform)
            const float x1 = x[(size_t)(row0 + r) * IN_DIM + k + 1];
            a1[r].x = fminf(a1[r].x, fminf(x0 + w1a.x, x1 + w1b.x));
            a1[r].y = fminf(a1[r].y, fminf(x0 + w1a.y, x1 + w1b.y));
            am[r].x = fminf(am[r].x, fminf(x0 + wma.x, x1 + wmb.x));
            am[r].y = fminf(am[r].y, fminf(x0 + wma.y, x1 + wmb.y));
        }
    }

    #pragma unroll
    for (int r = 0; r < RB; ++r) {
        part[c][0][r][jp] = a1[r];
        part[c][1][r][jp] = am[r];
    }
    __syncthreads();   // B1

    // ---- reduce1: h[p][r][j] = min over chunks; written IN-PLACE into part[0] ----
    {
        const int t = threadIdx.y * JP + threadIdx.x;   // 0..1023 = [2][4][128]
        const int p = t >> 9;
        const int r = (t >> 7) & 3;
        const int q = t & 127;
        float2 v = part[0][p][r][q];
        #pragma unroll
        for (int cc = 1; cc < KC; ++cc) {
            const float2 u = part[cc][p][r][q];
            v.x = fminf(v.x, u.x);
            v.y = fminf(v.y, u.y);
        }
        part[0][p][r][q] = v;   // own slot only -> race-free
    }
    __syncthreads();   // B2: h ready in part[0]

    // ================= stage 2: max-plus, K = 256, chunk = 32 i =================
    const float* W2p = W2 + j0;
    const float* Wsp = Ws + j0;

    float2 c1[RB], cm[RB];
    #pragma unroll
    for (int r = 0; r < RB; ++r) {
        c1[r].x = -INF; c1[r].y = -INF;
        cm[r].x = -INF; cm[r].y = -INF;
    }

    const int ipb = c * (OUT_DIM / KC / 2);   // 16 i-pairs per chunk

    #pragma unroll 4
    for (int ii = 0; ii < OUT_DIM / KC / 2; ++ii) {
        const int ip = ipb + ii;
        const int i  = ip * 2;
        const float2 w2a = *(const float2*)(W2p + (size_t)i       * OUT_DIM);
        const float2 w2b = *(const float2*)(W2p + (size_t)(i + 1) * OUT_DIM);
        const float2 wsa = *(const float2*)(Wsp + (size_t)i       * OUT_DIM);
        const float2 wsb = *(const float2*)(Wsp + (size_t)(i + 1) * OUT_DIM);
        #pragma unroll
        for (int r = 0; r < RB; ++r) {
            const float2 h01 = part[0][0][r][ip];   // uniform LDS broadcast
            const float2 g01 = part[0][1][r][ip];
            c1[r].x = fmaxf(c1[r].x, fmaxf(h01.x + w2a.x, h01.y + w2b.x));
            c1[r].y = fmaxf(c1[r].y, fmaxf(h01.x + w2a.y, h01.y + w2b.y));
            cm[r].x = fmaxf(cm[r].x, fmaxf(g01.x + wsa.x, g01.y + wsb.x));
            cm[r].y = fmaxf(cm[r].y, fmaxf(g01.x + wsa.y, g01.y + wsb.y));
        }
    }

    __syncthreads();   // B3: all hs reads done before part is overwritten
    #pragma unroll
    for (int r = 0; r < RB; ++r) {
        part[c][0][r][jp] = c1[r];
        part[c][1][r][jp] = cm[r];
    }
    __syncthreads();   // B4

    // ---- reduce2 + epilogue: max over chunks, +bias, min(paths), store ----
    {
        const int t = threadIdx.y * JP + threadIdx.x;
        if (t < 512) {                       // [4 rows][128 colpairs]
            const int r = t >> 7;
            const int q = t & 127;
            float2 m1 = part[0][0][r][q];
            float2 mm = part[0][1][r][q];
            #pragma unroll
            for (int cc = 1; cc < KC; ++cc) {
                const float2 u1 = part[cc][0][r][q];
                const float2 um = part[cc][1][r][q];
                m1.x = fmaxf(m1.x, u1.x); m1.y = fmaxf(m1.y, u1.y);
                mm.x = fmaxf(mm.x, um.x); mm.y = fmaxf(mm.y, um.y);
            }
            const float2 bb2 = *(const float2*)(b2 + 2 * q);
            const float2 bbs = *(const float2*)(bs + 2 * q);
            float2 o;
            o.x = fminf(m1.x + bb2.x, mm.x + bbs.x);
            o.y = fminf(m1.y + bb2.y, mm.y + bbs.y);
            *(float2*)(out + (size_t)(row0 + r) * OUT_DIM + 2 * q) = o;
        }
    }
}

extern "C" void kernel_launch(void* const* d_in, const int* in_sizes, int n_in,
                              void* d_out, int out_size, void* d_ws, size_t ws_size,
                              hipStream_t stream) {
    const float* x  = (const float*)d_in[0];
    const float* W1 = (const float*)d_in[1];
    const float* W2 = (const float*)d_in[2];
    const float* b2 = (const float*)d_in[3];
    const float* Wm = (const float*)d_in[4];
    const float* Ws = (const float*)d_in[5];
    const float* bs = (const float*)d_in[6];
    float* out = (float*)d_out;

    dim3 grid(BATCH / RB);     // 256 blocks = 1 per CU
    dim3 block(JP, KC);        // 1024 threads = 16 waves = 4/SIMD
    tropical_fused<<<grid, block, 0, stream>>>(x, W1, W2, b2, Wm, Ws, bs, out);
}